// Round 2
// 550.287 us; speedup vs baseline: 1.0403x; 1.0403x over previous
//
#include <hip/hip_runtime.h>

typedef __attribute__((ext_vector_type(8))) short short8;
typedef __attribute__((ext_vector_type(4))) float floatx4;

__device__ __forceinline__ unsigned short f2bf(float f) {
  union { float f; unsigned int u; } x; x.f = f;
  unsigned int r = (x.u + 0x7fffu + ((x.u >> 16) & 1u)) >> 16;
  return (unsigned short)r;
}
__device__ __forceinline__ float bf2f(unsigned short u) {
  union { unsigned int u; float f; } x; x.u = ((unsigned int)u) << 16;
  return x.f;
}

__device__ __forceinline__ void gload_lds16(const void* g, void* l) {
  __builtin_amdgcn_global_load_lds((const __attribute__((address_space(1))) void*)g,
                                   (__attribute__((address_space(3))) void*)l,
                                   16, 0, 0);
}

// ---------------------------------------------------------------------------
// Prep: densify masked weights to bf16 into one [3072][1024] Wqkv buffer:
// rows 0-1023 = Wc = (Wl*mask)@(Wq*mask) (<=81 nnz/row), 1024+ = Wk*mask,
// 2048+ = Wv*mask (25 nnz). biasAll[3072] = [ (Wl*mask)@bq | bk | bv ].
// ---------------------------------------------------------------------------
__global__ __launch_bounds__(128) void prep_weights(
    const float* __restrict__ Wq, const float* __restrict__ Wk,
    const float* __restrict__ Wv, const float* __restrict__ Wl,
    const float* __restrict__ bq, const float* __restrict__ bk,
    const float* __restrict__ bv,
    unsigned short* __restrict__ Wqkv, float* __restrict__ biasAll) {
  const int i = blockIdx.x;
  const int r = i >> 5, c = i & 31;
  const int t = threadIdx.x;
  for (int p = t; p < 1024; p += 128) {
    Wqkv[i * 1024 + p] = 0;
    Wqkv[(1024 + i) * 1024 + p] = 0;
    Wqkv[(2048 + i) * 1024 + p] = 0;
  }
  __syncthreads();
  if (t < 25) {
    int dr = t / 5 - 2, dc = t % 5 - 2;
    int j = (((r + dr) & 31) << 5) | ((c + dc) & 31);
    Wqkv[(1024 + i) * 1024 + j] = f2bf(Wk[i * 1024 + j]);
    Wqkv[(2048 + i) * 1024 + j] = f2bf(Wv[i * 1024 + j]);
  }
  if (t < 81) {
    int dr = t / 9 - 4, dc = t % 9 - 4;
    int j = (((r + dr) & 31) << 5) | ((c + dc) & 31);
    float s = 0.f;
    int erlo = dr - 2 < -2 ? -2 : dr - 2, erhi = dr + 2 > 2 ? 2 : dr + 2;
    int eclo = dc - 2 < -2 ? -2 : dc - 2, echi = dc + 2 > 2 ? 2 : dc + 2;
    for (int er = erlo; er <= erhi; ++er)
      for (int ec = eclo; ec <= echi; ++ec) {
        int m = (((r + er) & 31) << 5) | ((c + ec) & 31);
        s += Wl[i * 1024 + m] * Wq[m * 1024 + j];
      }
    Wqkv[i * 1024 + j] = f2bf(s);
  }
  if (t == 96) {
    float s = 0.f;
    for (int e = 0; e < 25; ++e) {
      int dr = e / 5 - 2, dc = e % 5 - 2;
      int m = (((r + dr) & 31) << 5) | ((c + dc) & 31);
      s += Wl[i * 1024 + m] * bq[m];
    }
    biasAll[i] = s;
  }
  if (t == 97) biasAll[1024 + i] = bk[i];
  if (t == 98) biasAll[2048 + i] = bv[i];
}

// ---------------------------------------------------------------------------
__global__ __launch_bounds__(256) void cast_bf16(const float4* __restrict__ x,
                                                 ushort4* __restrict__ xb) {
  int i = blockIdx.x * 256 + threadIdx.x;
  float4 v = x[i];
  ushort4 o;
  o.x = f2bf(v.x); o.y = f2bf(v.y); o.z = f2bf(v.z); o.w = f2bf(v.w);
  xb[i] = o;
}

// ---------------------------------------------------------------------------
// 256x256-tile, BK=64, 8-wave (2Mx4N), deep-pipelined GEMM (m201-style
// 8-phase schedule in plain HIP): C[m,n] = sum_k A[m,k]*B[n,k].
// Per K-tile: 4 phases = C-quadrants (mh,nh) in order (0,0)(0,1)(1,1)(1,0);
// quarter-granular staging (64 rows x 64 cols = 1 gload_lds/thread) with a
// counted s_waitcnt vmcnt(2) once per tile (a0,a2 of tile t+2 allowed in
// flight). XOR swizzle (g ^ (row&7)) on both stage-source and ds_read.
// OUTMODE 0: bf16 out + fp32 bias[col] (QKV projection)
// OUTMODE 2: e=exp(acc*scale) bf16 out; per-row partial sums -> Lpart[row*8+bn]
// OUTMODE 3: fp32 out * invL[row] (PV with deferred softmax normalization)
// ---------------------------------------------------------------------------
template <int OUTMODE>
__global__ __launch_bounds__(512, 2) void gemm256(
    const unsigned short* __restrict__ A, const unsigned short* __restrict__ B,
    void* __restrict__ Cv, const float* __restrict__ auxc, float* __restrict__ auxw,
    int lda, int ldb, int ldc, int K, float scale,
    size_t sA, size_t sB, size_t sC) {
  // [2 buf][A 256x64 | B 256x64] bf16 = 128 KiB
  __shared__ __align__(16) unsigned short lds[65536];
  const int t = threadIdx.x;
  const int lane = t & 63;
  const int wv = t >> 6;          // 0..7
  const int wm = wv >> 2;         // 0..1  (row half)
  const int wn = wv & 3;          // 0..3  (col quarter)
  const int l15 = lane & 15, lq = lane >> 4;
  const int bm = blockIdx.y, bn = blockIdx.x, bz = blockIdx.z;
  A += sA * bz; B += sB * bz;

  const int rl = t >> 3;                 // staging row within quarter 0..63
  const int gd = (t & 7) ^ (rl & 7);     // pre-swizzled 16B-group in source
  const int wb = (t >> 6) << 9;          // wave base (elements) within quarter

#define STAGE_A(q, tt_)                                                        \
  gload_lds16(A + (size_t)(bm * 256 + (q) * 64 + rl) * lda + (tt_) * 64 + gd * 8, \
              &lds[(((tt_) & 1) << 14) + ((q) << 12) + wb])
#define STAGE_B(q, tt_)                                                        \
  gload_lds16(B + (size_t)(bn * 256 + (q) * 64 + rl) * ldb + (tt_) * 64 + gd * 8, \
              &lds[32768 + (((tt_) & 1) << 14) + ((q) << 12) + wb])

  floatx4 acc[8][4];
#pragma unroll
  for (int i = 0; i < 8; ++i)
#pragma unroll
    for (int j = 0; j < 4; ++j) acc[i][j] = (floatx4){0.f, 0.f, 0.f, 0.f};

  const int NT = K >> 6;  // assumed >= 2 (K is 1024 or 2048 here)

  // Prologue: all 8 quarters of tile 0, then a0,a2 of tile 1 (the 2 that
  // vmcnt(2) is allowed to leave outstanding).
  STAGE_A(0, 0); STAGE_A(1, 0); STAGE_A(2, 0); STAGE_A(3, 0);
  STAGE_B(0, 0); STAGE_B(1, 0); STAGE_B(2, 0); STAGE_B(3, 0);
  asm volatile("" ::: "memory");   // keep issue order: tile0 before tile1
  STAGE_A(0, 1); STAGE_A(2, 1);
  asm volatile("s_waitcnt vmcnt(2)" ::: "memory");
  __builtin_amdgcn_s_barrier();

  for (int tt = 0; tt < NT; ++tt) {
    const int bo = (tt & 1) << 14;  // element offset of current buffer
    short8 aF[4][2], bFa[2][2], bFb[2][2];

    // ---- phase 0: quadrant (mh=0, nh=0) -------------------------------
#pragma unroll
    for (int i = 0; i < 4; ++i) {
      int rA = wm * 128 + i * 16 + l15;
#pragma unroll
      for (int ks = 0; ks < 2; ++ks) {
        int g = ks * 4 + lq;
        aF[i][ks] = *(const short8*)&lds[bo + rA * 64 + ((g ^ (rA & 7)) << 3)];
      }
    }
#pragma unroll
    for (int j = 0; j < 2; ++j) {
      int rB = wn * 64 + j * 16 + l15;
#pragma unroll
      for (int ks = 0; ks < 2; ++ks) {
        int g = ks * 4 + lq;
        bFa[j][ks] = *(const short8*)&lds[32768 + bo + rB * 64 + ((g ^ (rB & 7)) << 3)];
      }
    }
    if (tt + 1 < NT) { STAGE_A(1, tt + 1); STAGE_A(3, tt + 1); STAGE_B(2, tt + 1); STAGE_B(3, tt + 1); }
    __builtin_amdgcn_s_barrier();
    __builtin_amdgcn_s_setprio(1);
#pragma unroll
    for (int i = 0; i < 4; ++i)
#pragma unroll
      for (int j = 0; j < 2; ++j) {
        acc[i][j] = __builtin_amdgcn_mfma_f32_16x16x32_bf16(aF[i][0], bFa[j][0], acc[i][j], 0, 0, 0);
        acc[i][j] = __builtin_amdgcn_mfma_f32_16x16x32_bf16(aF[i][1], bFa[j][1], acc[i][j], 0, 0, 0);
      }
    __builtin_amdgcn_s_setprio(0);
    asm volatile("s_waitcnt lgkmcnt(0)" ::: "memory");
    __builtin_amdgcn_s_barrier();

    // ---- phase 1: quadrant (mh=0, nh=1) -------------------------------
#pragma unroll
    for (int j = 0; j < 2; ++j) {
      int rB = wn * 64 + 32 + j * 16 + l15;
#pragma unroll
      for (int ks = 0; ks < 2; ++ks) {
        int g = ks * 4 + lq;
        bFb[j][ks] = *(const short8*)&lds[32768 + bo + rB * 64 + ((g ^ (rB & 7)) << 3)];
      }
    }
    if (tt + 1 < NT) { STAGE_B(0, tt + 1); STAGE_B(1, tt + 1); }
    __builtin_amdgcn_s_barrier();
    __builtin_amdgcn_s_setprio(1);
#pragma unroll
    for (int i = 0; i < 4; ++i)
#pragma unroll
      for (int j = 0; j < 2; ++j) {
        acc[i][2 + j] = __builtin_amdgcn_mfma_f32_16x16x32_bf16(aF[i][0], bFb[j][0], acc[i][2 + j], 0, 0, 0);
        acc[i][2 + j] = __builtin_amdgcn_mfma_f32_16x16x32_bf16(aF[i][1], bFb[j][1], acc[i][2 + j], 0, 0, 0);
      }
    __builtin_amdgcn_s_setprio(0);
    asm volatile("s_waitcnt lgkmcnt(0)" ::: "memory");
    __builtin_amdgcn_s_barrier();

    // ---- phase 2: quadrant (mh=1, nh=1) -------------------------------
#pragma unroll
    for (int i = 0; i < 4; ++i) {
      int rA = wm * 128 + 64 + i * 16 + l15;
#pragma unroll
      for (int ks = 0; ks < 2; ++ks) {
        int g = ks * 4 + lq;
        aF[i][ks] = *(const short8*)&lds[bo + rA * 64 + ((g ^ (rA & 7)) << 3)];
      }
    }
    if (tt + 2 < NT) { STAGE_A(0, tt + 2); STAGE_A(2, tt + 2); }
    __builtin_amdgcn_s_barrier();
    __builtin_amdgcn_s_setprio(1);
#pragma unroll
    for (int i = 0; i < 4; ++i)
#pragma unroll
      for (int j = 0; j < 2; ++j) {
        acc[4 + i][2 + j] = __builtin_amdgcn_mfma_f32_16x16x32_bf16(aF[i][0], bFb[j][0], acc[4 + i][2 + j], 0, 0, 0);
        acc[4 + i][2 + j] = __builtin_amdgcn_mfma_f32_16x16x32_bf16(aF[i][1], bFb[j][1], acc[4 + i][2 + j], 0, 0, 0);
      }
    __builtin_amdgcn_s_setprio(0);
    asm volatile("s_waitcnt lgkmcnt(0)" ::: "memory");
    __builtin_amdgcn_s_barrier();

    // ---- phase 3: quadrant (mh=1, nh=0) — no reads, no stages ---------
    __builtin_amdgcn_s_setprio(1);
#pragma unroll
    for (int i = 0; i < 4; ++i)
#pragma unroll
      for (int j = 0; j < 2; ++j) {
        acc[4 + i][j] = __builtin_amdgcn_mfma_f32_16x16x32_bf16(aF[i][0], bFa[j][0], acc[4 + i][j], 0, 0, 0);
        acc[4 + i][j] = __builtin_amdgcn_mfma_f32_16x16x32_bf16(aF[i][1], bFa[j][1], acc[4 + i][j], 0, 0, 0);
      }
    __builtin_amdgcn_s_setprio(0);
    if (tt < NT - 2)       { asm volatile("s_waitcnt vmcnt(2)" ::: "memory"); }
    else if (tt == NT - 2) { asm volatile("s_waitcnt vmcnt(0)" ::: "memory"); }
    __builtin_amdgcn_s_barrier();
  }
#undef STAGE_A
#undef STAGE_B

  // acc[m][n]: row = row0 + (m>>2)*64 + (m&3)*16 + lq*4 + r2
  //            col = col0 + (n>>1)*32 + (n&1)*16 + l15
  const int row0 = bm * 256 + wm * 128;
  const int col0 = bn * 256 + wn * 64;

  if (OUTMODE == 0) {
    unsigned short* C = (unsigned short*)Cv + sC * bz;
#pragma unroll
    for (int m = 0; m < 8; ++m) {
      int rb = row0 + ((m >> 2) << 6) + ((m & 3) << 4) + (lq << 2);
#pragma unroll
      for (int n = 0; n < 4; ++n) {
        int col = col0 + ((n >> 1) << 5) + ((n & 1) << 4) + l15;
        float bb = auxc[col];
#pragma unroll
        for (int r2 = 0; r2 < 4; ++r2)
          C[(size_t)(rb + r2) * ldc + col] = f2bf(acc[m][n][r2] + bb);
      }
    }
  } else if (OUTMODE == 2) {
    unsigned short* C = (unsigned short*)Cv + sC * bz;
    float p[8][4];
#pragma unroll
    for (int m = 0; m < 8; ++m)
#pragma unroll
      for (int r2 = 0; r2 < 4; ++r2) p[m][r2] = 0.f;
#pragma unroll
    for (int m = 0; m < 8; ++m) {
      int rb = row0 + ((m >> 2) << 6) + ((m & 3) << 4) + (lq << 2);
#pragma unroll
      for (int n = 0; n < 4; ++n) {
        int col = col0 + ((n >> 1) << 5) + ((n & 1) << 4) + l15;
#pragma unroll
        for (int r2 = 0; r2 < 4; ++r2) {
          float e = __expf(acc[m][n][r2] * scale);
          C[(size_t)(rb + r2) * ldc + col] = f2bf(e);
          p[m][r2] += e;
        }
      }
    }
    // reduce over the 16 lanes (l15) sharing each row
#pragma unroll
    for (int m = 0; m < 8; ++m)
#pragma unroll
      for (int r2 = 0; r2 < 4; ++r2) {
        float v = p[m][r2];
        v += __shfl_xor(v, 1); v += __shfl_xor(v, 2);
        v += __shfl_xor(v, 4); v += __shfl_xor(v, 8);
        p[m][r2] = v;
      }
    float* sred = (float*)lds;  // [4 wn][256 rows]; LDS reads all drained
    if (l15 == 0) {
#pragma unroll
      for (int m = 0; m < 8; ++m)
#pragma unroll
        for (int r2 = 0; r2 < 4; ++r2)
          sred[wn * 256 + wm * 128 + ((m >> 2) << 6) + ((m & 3) << 4) + (lq << 2) + r2] = p[m][r2];
    }
    __syncthreads();
    if (t < 256) {
      float L = sred[t] + sred[256 + t] + sred[512 + t] + sred[768 + t];
      auxw[((size_t)bz * 2048 + bm * 256 + t) * 8 + bn] = L;
    }
  } else {  // OUTMODE 3
    float* C = (float*)Cv + sC * bz;
#pragma unroll
    for (int m = 0; m < 8; ++m) {
      int rb = row0 + ((m >> 2) << 6) + ((m & 3) << 4) + (lq << 2);
      float il[4];
#pragma unroll
      for (int r2 = 0; r2 < 4; ++r2)
        il[r2] = auxc[(size_t)bz * 2048 + rb + r2];
#pragma unroll
      for (int n = 0; n < 4; ++n) {
        int col = col0 + ((n >> 1) << 5) + ((n & 1) << 4) + l15;
#pragma unroll
        for (int r2 = 0; r2 < 4; ++r2)
          C[(size_t)(rb + r2) * ldc + col] = acc[m][n][r2] * il[r2];
      }
    }
  }
}

// ---------------------------------------------------------------------------
// v part of qkv [16384][3072] (cols 2048+) -> vT [B][H][S] bf16
// ---------------------------------------------------------------------------
__global__ __launch_bounds__(1024) void transpose_v(const unsigned short* __restrict__ qkv,
                                                    unsigned short* __restrict__ vT) {
  __shared__ unsigned short tile[32][33];
  int s0 = blockIdx.x * 32, h0 = blockIdx.y * 32, b = blockIdx.z;
  int tx = threadIdx.x, ty = threadIdx.y;
  tile[ty][tx] = qkv[((size_t)b * 2048 + s0 + ty) * 3072 + 2048 + h0 + tx];
  __syncthreads();
  vT[((size_t)b * 1024 + h0 + ty) * 2048 + s0 + tx] = tile[tx][ty];
}

// ---------------------------------------------------------------------------
// Finish softmax: per row, L = sum of 8 partials; invL = 1/L; write probs
// fp32 = e(bf16) * invL.  One block (256 thr) per row.
// ---------------------------------------------------------------------------
__global__ __launch_bounds__(256) void finish_softmax(
    const float* __restrict__ Lpart, const unsigned short* __restrict__ pb,
    float* __restrict__ invL, float* __restrict__ probs) {
  const size_t row = blockIdx.x;
  const int t = threadIdx.x;
  __shared__ float sInv;
  if (t < 64) {
    float s = (t < 8) ? Lpart[row * 8 + t] : 0.f;
    s += __shfl_xor(s, 1); s += __shfl_xor(s, 2); s += __shfl_xor(s, 4);
    if (t == 0) {
      float inv = 1.0f / s;
      sInv = inv;
      invL[row] = inv;
    }
  }
  __syncthreads();
  float inv = sInv;
  const ushort4* pv = (const ushort4*)(pb + row * 2048);
  float4* pr = (float4*)(probs + row * 2048);
  ushort4 a = pv[t * 2], b = pv[t * 2 + 1];
  float4 o0, o1;
  o0.x = bf2f(a.x) * inv; o0.y = bf2f(a.y) * inv;
  o0.z = bf2f(a.z) * inv; o0.w = bf2f(a.w) * inv;
  o1.x = bf2f(b.x) * inv; o1.y = bf2f(b.y) * inv;
  o1.z = bf2f(b.z) * inv; o1.w = bf2f(b.w) * inv;
  pr[t * 2] = o0; pr[t * 2 + 1] = o1;
}

// ---------------------------------------------------------------------------
extern "C" void kernel_launch(void* const* d_in, const int* in_sizes, int n_in,
                              void* d_out, int out_size, void* d_ws, size_t ws_size,
                              hipStream_t stream) {
  const float* x  = (const float*)d_in[0];
  const float* Wq = (const float*)d_in[1];
  const float* bq = (const float*)d_in[2];
  const float* Wk = (const float*)d_in[3];
  const float* bk = (const float*)d_in[4];
  const float* Wv = (const float*)d_in[5];
  const float* bv = (const float*)d_in[6];
  const float* Wl = (const float*)d_in[7];

  const int B = 8, S = 2048, H = 1024;
  float* out   = (float*)d_out;                     // [B,S,H]
  float* probs = (float*)d_out + (size_t)B * S * H; // [B,S,S]

  char* ws = (char*)d_ws;
  unsigned short* qkv  = (unsigned short*)(ws + 0);           // 100.7MB [16384][3072]
  unsigned short* pb   = (unsigned short*)(ws + 100663296);   // 67MB [B*S][2048] e=exp(s)
  unsigned short* xb   = (unsigned short*)(ws + 167772160);   // 33.5MB (dead after QKV GEMM)
  unsigned short* vT   = (unsigned short*)(ws + 167772160);   // 33.5MB overlays xb
  unsigned short* Wqkv = (unsigned short*)(ws + 201326592);   // 6.3MB [3072][1024]
  float* biasAll       = (float*)(ws + 207618048);            // 12KB
  float* Lpart         = (float*)(ws + 207630336);            // 512KB [16384][8]
  float* invL          = (float*)(ws + 208678912);            // 64KB [16384]

  prep_weights<<<1024, 128, 0, stream>>>(Wq, Wk, Wv, Wl, bq, bk, bv, Wqkv, biasAll);
  cast_bf16<<<16384, 256, 0, stream>>>((const float4*)x, (ushort4*)xb);

  // qkv = x @ Wqkv^T + biasAll   [16384][3072] bf16
  gemm256<0><<<dim3(12, 64, 1), 512, 0, stream>>>(xb, Wqkv, qkv, biasAll, nullptr,
      H, H, 3 * H, H, 1.f, 0, 0, 0);

  transpose_v<<<dim3(64, 32, 8), dim3(32, 32), 0, stream>>>(qkv, vT);

  // e = exp(q@k^T/32) bf16 -> pb, row-block partial sums -> Lpart
  gemm256<2><<<dim3(8, 8, 8), 512, 0, stream>>>(qkv, qkv + 1024, pb, nullptr, Lpart,
      3 * H, 3 * H, S, H, 1.0f / 32.0f, (size_t)S * 3 * H, (size_t)S * 3 * H, (size_t)S * S);

  finish_softmax<<<16384, 256, 0, stream>>>(Lpart, pb, invL, probs);

  // out = (e @ v) * invL[row]
  gemm256<3><<<dim3(4, 8, 8), 512, 0, stream>>>(pb, vT, out, invL, nullptr,
      S, S, H, S, 1.0f, (size_t)S * S, (size_t)H * S, (size_t)S * H);
}

// Round 3
// 541.272 us; speedup vs baseline: 1.0576x; 1.0167x over previous
//
#include <hip/hip_runtime.h>

typedef __attribute__((ext_vector_type(8))) short short8;
typedef __attribute__((ext_vector_type(4))) float floatx4;

__device__ __forceinline__ unsigned short f2bf(float f) {
  union { float f; unsigned int u; } x; x.f = f;
  unsigned int r = (x.u + 0x7fffu + ((x.u >> 16) & 1u)) >> 16;
  return (unsigned short)r;
}
__device__ __forceinline__ float bf2f(unsigned short u) {
  union { unsigned int u; float f; } x; x.u = ((unsigned int)u) << 16;
  return x.f;
}

__device__ __forceinline__ void gload_lds16(const void* g, void* l) {
  __builtin_amdgcn_global_load_lds((const __attribute__((address_space(1))) void*)g,
                                   (__attribute__((address_space(3))) void*)l,
                                   16, 0, 0);
}

// ---------------------------------------------------------------------------
// Prep: densify masked weights to bf16 into one [3072][1024] Wqkv buffer:
// rows 0-1023 = Wc = (Wl*mask)@(Wq*mask) (<=81 nnz/row), 1024+ = Wk*mask,
// 2048+ = Wv*mask (25 nnz). biasAll[3072] = [ (Wl*mask)@bq | bk | bv ].
// ---------------------------------------------------------------------------
__global__ __launch_bounds__(128) void prep_weights(
    const float* __restrict__ Wq, const float* __restrict__ Wk,
    const float* __restrict__ Wv, const float* __restrict__ Wl,
    const float* __restrict__ bq, const float* __restrict__ bk,
    const float* __restrict__ bv,
    unsigned short* __restrict__ Wqkv, float* __restrict__ biasAll) {
  const int i = blockIdx.x;
  const int r = i >> 5, c = i & 31;
  const int t = threadIdx.x;
  for (int p = t; p < 1024; p += 128) {
    Wqkv[i * 1024 + p] = 0;
    Wqkv[(1024 + i) * 1024 + p] = 0;
    Wqkv[(2048 + i) * 1024 + p] = 0;
  }
  __syncthreads();
  if (t < 25) {
    int dr = t / 5 - 2, dc = t % 5 - 2;
    int j = (((r + dr) & 31) << 5) | ((c + dc) & 31);
    Wqkv[(1024 + i) * 1024 + j] = f2bf(Wk[i * 1024 + j]);
    Wqkv[(2048 + i) * 1024 + j] = f2bf(Wv[i * 1024 + j]);
  }
  if (t < 81) {
    int dr = t / 9 - 4, dc = t % 9 - 4;
    int j = (((r + dr) & 31) << 5) | ((c + dc) & 31);
    float s = 0.f;
    int erlo = dr - 2 < -2 ? -2 : dr - 2, erhi = dr + 2 > 2 ? 2 : dr + 2;
    int eclo = dc - 2 < -2 ? -2 : dc - 2, echi = dc + 2 > 2 ? 2 : dc + 2;
    for (int er = erlo; er <= erhi; ++er)
      for (int ec = eclo; ec <= echi; ++ec) {
        int m = (((r + er) & 31) << 5) | ((c + ec) & 31);
        s += Wl[i * 1024 + m] * Wq[m * 1024 + j];
      }
    Wqkv[i * 1024 + j] = f2bf(s);
  }
  if (t == 96) {
    float s = 0.f;
    for (int e = 0; e < 25; ++e) {
      int dr = e / 5 - 2, dc = e % 5 - 2;
      int m = (((r + dr) & 31) << 5) | ((c + dc) & 31);
      s += Wl[i * 1024 + m] * bq[m];
    }
    biasAll[i] = s;
  }
  if (t == 97) biasAll[1024 + i] = bk[i];
  if (t == 98) biasAll[2048 + i] = bv[i];
}

// ---------------------------------------------------------------------------
__global__ __launch_bounds__(256) void cast_bf16(const float4* __restrict__ x,
                                                 ushort4* __restrict__ xb) {
  int i = blockIdx.x * 256 + threadIdx.x;
  float4 v = x[i];
  ushort4 o;
  o.x = f2bf(v.x); o.y = f2bf(v.y); o.z = f2bf(v.z); o.w = f2bf(v.w);
  xb[i] = o;
}

// ---------------------------------------------------------------------------
// 256x256-tile, BK=64, 8-wave (2Mx4N) GEMM with the verified m201 cadence:
// iteration = 2 K-tiles, 8 phases; ONE half-tile (128rows x 64 cols, 2
// gload_lds/thread) staged per stage-slot; counted vmcnt(4)@ph4 / vmcnt(6)@ph8
// only (never 0 mid-loop). Stage slots chosen so every target region is
// read-complete >=1 barrier before issue (same-buffer T->T+2 WAR safe):
//   ph1: A1(T+1) | ph3: B0(T+2) | ph4: A0(T+2) | ph5: B1,A1(T+2)
//   ph7: B0(T+3) | ph8: A0,B1(T+3)
// Ledger (steady): @ph4 outstanding 12 loads, vmcnt(4) retires through
// A1(T+1) -> tile T+1 resident; @ph8 outstanding 14, vmcnt(6) retires through
// A1(T+2) -> tile T+2 resident; leaves 3 half-tiles in flight (invariant).
// XOR swizzle (g ^ (row&7)) on stage-source and ds_read (both-sides).
// OUTMODE 0: bf16 out + fp32 bias[col]; OUTMODE 2: e=exp(acc*scale) bf16 out
// + row partials -> Lpart[row*8+bn]; OUTMODE 3: fp32 out * invL[row].
// ---------------------------------------------------------------------------
template <int OUTMODE>
__global__ __launch_bounds__(512, 2) void gemm256(
    const unsigned short* __restrict__ A, const unsigned short* __restrict__ B,
    void* __restrict__ Cv, const float* __restrict__ auxc, float* __restrict__ auxw,
    int lda, int ldb, int ldc, int K, float scale,
    size_t sA, size_t sB, size_t sC) {
  // [2 buf][A 256x64 | B 256x64] bf16 = 128 KiB
  __shared__ __align__(16) unsigned short lds[65536];
  const int t = threadIdx.x;
  const int lane = t & 63;
  const int wv = t >> 6;          // 0..7
  const int wm = wv >> 2;         // 0..1  (row half)
  const int wn = wv & 3;          // 0..3  (col quarter)
  const int l15 = lane & 15, lq = lane >> 4;
  const int bm = blockIdx.y, bn = blockIdx.x, bz = blockIdx.z;
  A += sA * bz; B += sB * bz;

  const int srow = t >> 3;               // staging row within half 0..63
  const int sg = (t & 7) ^ (srow & 7);   // pre-swizzled 16B-group in source

  // Stage one half-tile (128 rows x 64 cols): 2 gload_lds x 512 thr x 16B.
#define STG_A(h, tile_) do {                                                     \
    gload_lds16(A + (size_t)(bm * 256 + (h) * 128 + srow) * lda + (tile_) * 64 + sg * 8, \
                &lds[(((tile_) & 1) << 14) + (h) * 8192 + wv * 512]);            \
    gload_lds16(A + (size_t)(bm * 256 + (h) * 128 + 64 + srow) * lda + (tile_) * 64 + sg * 8, \
                &lds[(((tile_) & 1) << 14) + (h) * 8192 + 4096 + wv * 512]);     \
  } while (0)
#define STG_B(h, tile_) do {                                                     \
    gload_lds16(B + (size_t)(bn * 256 + (h) * 128 + srow) * ldb + (tile_) * 64 + sg * 8, \
                &lds[32768 + (((tile_) & 1) << 14) + (h) * 8192 + wv * 512]);    \
    gload_lds16(B + (size_t)(bn * 256 + (h) * 128 + 64 + srow) * ldb + (tile_) * 64 + sg * 8, \
                &lds[32768 + (((tile_) & 1) << 14) + (h) * 8192 + 4096 + wv * 512]); \
  } while (0)

#define LOADA(arr, ro)                                                           \
  _Pragma("unroll") for (int i = 0; i < 4; ++i) {                                \
    int rA = wm * 128 + (ro) + i * 16 + l15;                                     \
    _Pragma("unroll") for (int ks = 0; ks < 2; ++ks)                             \
      arr[i][ks] = *(const short8*)&lds[bo_ + rA * 64 + (((ks * 4 + lq) ^ (rA & 7)) << 3)]; \
  }
#define LOADB(arr, ro)                                                           \
  _Pragma("unroll") for (int j = 0; j < 2; ++j) {                                \
    int rB = wn * 64 + (ro) + j * 16 + l15;                                      \
    _Pragma("unroll") for (int ks = 0; ks < 2; ++ks)                             \
      arr[j][ks] = *(const short8*)&lds[32768 + bo_ + rB * 64 + (((ks * 4 + lq) ^ (rB & 7)) << 3)]; \
  }
#define MFMA8(mb, nb, aa, bb)                                                    \
  _Pragma("unroll") for (int i = 0; i < 4; ++i)                                  \
    _Pragma("unroll") for (int j = 0; j < 2; ++j) {                              \
      acc[(mb) + i][(nb) + j] = __builtin_amdgcn_mfma_f32_16x16x32_bf16(         \
          aa[i][0], bb[j][0], acc[(mb) + i][(nb) + j], 0, 0, 0);                 \
      acc[(mb) + i][(nb) + j] = __builtin_amdgcn_mfma_f32_16x16x32_bf16(         \
          aa[i][1], bb[j][1], acc[(mb) + i][(nb) + j], 0, 0, 0);                 \
    }
#define FENCE asm volatile("" ::: "memory")
#define BAR __builtin_amdgcn_s_barrier()
#define SP1 __builtin_amdgcn_s_setprio(1)
#define SP0 __builtin_amdgcn_s_setprio(0)

  floatx4 acc[8][4];
#pragma unroll
  for (int i = 0; i < 8; ++i)
#pragma unroll
    for (int j = 0; j < 4; ++j) acc[i][j] = (floatx4){0.f, 0.f, 0.f, 0.f};

  const int NT = K >> 6;  // even, >= 2 (16 or 32 here)

  // Prologue: tile0 fully (8 loads) + B0,A0,B1 of tile1 (6 loads);
  // vmcnt(6) -> tile0 resident, 3 half-tiles of tile1 in flight.
  STG_A(0, 0); STG_A(1, 0); STG_B(0, 0); STG_B(1, 0);
  FENCE;
  STG_B(0, 1); STG_A(0, 1); STG_B(1, 1);
  asm volatile("s_waitcnt vmcnt(6)" ::: "memory");
  BAR;

  for (int T = 0; T < NT; T += 2) {
    short8 aF[4][2], bFa[2][2], bFb[2][2];
    // ================= tile T (buffer 0) =================
    {
      const int bo_ = 0;
      // ph1: Q(0,0)
      LOADA(aF, 0); LOADB(bFa, 0);
      STG_A(1, T + 1);
      FENCE; BAR;
      SP1; MFMA8(0, 0, aF, bFa); SP0;
      FENCE; BAR;
      // ph2: Q(0,1)
      LOADB(bFb, 32);
      FENCE; BAR;
      SP1; MFMA8(0, 2, aF, bFb); SP0;
      FENCE; BAR;
      // ph3: Q(1,1)  (reuse aF regs for upper A half)
      LOADA(aF, 64);
      if (T + 2 < NT) STG_B(0, T + 2);
      FENCE; BAR;
      SP1; MFMA8(4, 2, aF, bFb); SP0;
      FENCE; BAR;
      // ph4: Q(1,0)
      if (T + 2 < NT) STG_A(0, T + 2);
      FENCE; BAR;
      SP1; MFMA8(4, 0, aF, bFa); SP0;
      if (T + 2 < NT) { asm volatile("s_waitcnt vmcnt(4)" ::: "memory"); }
      else            { asm volatile("s_waitcnt vmcnt(0)" ::: "memory"); }
      FENCE; BAR;
    }
    // ================= tile T+1 (buffer 1) =================
    {
      const int bo_ = 1 << 14;
      // ph5: Q(0,0)
      LOADA(aF, 0); LOADB(bFa, 0);
      if (T + 2 < NT) { STG_B(1, T + 2); STG_A(1, T + 2); }
      FENCE; BAR;
      SP1; MFMA8(0, 0, aF, bFa); SP0;
      FENCE; BAR;
      // ph6: Q(0,1)
      LOADB(bFb, 32);
      FENCE; BAR;
      SP1; MFMA8(0, 2, aF, bFb); SP0;
      FENCE; BAR;
      // ph7: Q(1,1)
      LOADA(aF, 64);
      if (T + 3 < NT) STG_B(0, T + 3);
      FENCE; BAR;
      SP1; MFMA8(4, 2, aF, bFb); SP0;
      FENCE; BAR;
      // ph8: Q(1,0)
      if (T + 3 < NT) { STG_A(0, T + 3); STG_B(1, T + 3); }
      FENCE; BAR;
      SP1; MFMA8(4, 0, aF, bFa); SP0;
      if (T + 3 < NT) { asm volatile("s_waitcnt vmcnt(6)" ::: "memory"); }
      else            { asm volatile("s_waitcnt vmcnt(0)" ::: "memory"); }
      FENCE; BAR;
    }
  }
#undef STG_A
#undef STG_B
#undef LOADA
#undef LOADB
#undef MFMA8

  // acc[m][n]: row = row0 + (m>>2)*64 + (m&3)*16 + lq*4 + r2
  //            col = col0 + (n>>1)*32 + (n&1)*16 + l15
  const int row0 = bm * 256 + wm * 128;
  const int col0 = bn * 256 + wn * 64;

  if (OUTMODE == 0) {
    unsigned short* C = (unsigned short*)Cv + sC * bz;
#pragma unroll
    for (int m = 0; m < 8; ++m) {
      int rb = row0 + ((m >> 2) << 6) + ((m & 3) << 4) + (lq << 2);
#pragma unroll
      for (int n = 0; n < 4; ++n) {
        int col = col0 + ((n >> 1) << 5) + ((n & 1) << 4) + l15;
        float bb = auxc[col];
#pragma unroll
        for (int r2 = 0; r2 < 4; ++r2)
          C[(size_t)(rb + r2) * ldc + col] = f2bf(acc[m][n][r2] + bb);
      }
    }
  } else if (OUTMODE == 2) {
    unsigned short* C = (unsigned short*)Cv + sC * bz;
    float p[8][4];
#pragma unroll
    for (int m = 0; m < 8; ++m)
#pragma unroll
      for (int r2 = 0; r2 < 4; ++r2) p[m][r2] = 0.f;
#pragma unroll
    for (int m = 0; m < 8; ++m) {
      int rb = row0 + ((m >> 2) << 6) + ((m & 3) << 4) + (lq << 2);
#pragma unroll
      for (int n = 0; n < 4; ++n) {
        int col = col0 + ((n >> 1) << 5) + ((n & 1) << 4) + l15;
#pragma unroll
        for (int r2 = 0; r2 < 4; ++r2) {
          float e = __expf(acc[m][n][r2] * scale);
          C[(size_t)(rb + r2) * ldc + col] = f2bf(e);
          p[m][r2] += e;
        }
      }
    }
    // reduce over the 16 lanes (l15) sharing each row
#pragma unroll
    for (int m = 0; m < 8; ++m)
#pragma unroll
      for (int r2 = 0; r2 < 4; ++r2) {
        float v = p[m][r2];
        v += __shfl_xor(v, 1); v += __shfl_xor(v, 2);
        v += __shfl_xor(v, 4); v += __shfl_xor(v, 8);
        p[m][r2] = v;
      }
    float* sred = (float*)lds;  // [4 wn][256 rows]; all LDS traffic drained
    if (l15 == 0) {
#pragma unroll
      for (int m = 0; m < 8; ++m)
#pragma unroll
        for (int r2 = 0; r2 < 4; ++r2)
          sred[wn * 256 + wm * 128 + ((m >> 2) << 6) + ((m & 3) << 4) + (lq << 2) + r2] = p[m][r2];
    }
    __syncthreads();
    if (t < 256) {
      float L = sred[t] + sred[256 + t] + sred[512 + t] + sred[768 + t];
      auxw[((size_t)bz * 2048 + bm * 256 + t) * 8 + bn] = L;
    }
  } else {  // OUTMODE 3
    float* C = (float*)Cv + sC * bz;
#pragma unroll
    for (int m = 0; m < 8; ++m) {
      int rb = row0 + ((m >> 2) << 6) + ((m & 3) << 4) + (lq << 2);
      float il[4];
#pragma unroll
      for (int r2 = 0; r2 < 4; ++r2)
        il[r2] = auxc[(size_t)bz * 2048 + rb + r2];
#pragma unroll
      for (int n = 0; n < 4; ++n) {
        int col = col0 + ((n >> 1) << 5) + ((n & 1) << 4) + l15;
#pragma unroll
        for (int r2 = 0; r2 < 4; ++r2)
          C[(size_t)(rb + r2) * ldc + col] = acc[m][n][r2] * il[r2];
      }
    }
  }
}

// ---------------------------------------------------------------------------
// v part of qkv [16384][3072] (cols 2048+) -> vT [B][H][S] bf16.
// ushort4-vectorized both sides (8 B/lane).
// ---------------------------------------------------------------------------
__global__ __launch_bounds__(256) void transpose_v(const unsigned short* __restrict__ qkv,
                                                   unsigned short* __restrict__ vT) {
  __shared__ unsigned short tile[32][33];
  int s0 = blockIdx.x * 32, h0 = blockIdx.y * 32, b = blockIdx.z;
  int tx = threadIdx.x;  // 0..7
  int ty = threadIdx.y;  // 0..31
  ushort4 v = *(const ushort4*)&qkv[((size_t)b * 2048 + s0 + ty) * 3072 + 2048 + h0 + tx * 4];
  int c0 = tx * 4;
  tile[ty][c0 + 0] = v.x; tile[ty][c0 + 1] = v.y;
  tile[ty][c0 + 2] = v.z; tile[ty][c0 + 3] = v.w;
  __syncthreads();
  ushort4 o;
  o.x = tile[c0 + 0][ty]; o.y = tile[c0 + 1][ty];
  o.z = tile[c0 + 2][ty]; o.w = tile[c0 + 3][ty];
  *(ushort4*)&vT[((size_t)b * 1024 + h0 + ty) * 2048 + s0 + c0] = o;
}

// ---------------------------------------------------------------------------
// Finish softmax: per row, L = sum of 8 partials; invL = 1/L; write probs
// fp32 = e(bf16) * invL.  One block (256 thr) per row.
// ---------------------------------------------------------------------------
__global__ __launch_bounds__(256) void finish_softmax(
    const float* __restrict__ Lpart, const unsigned short* __restrict__ pb,
    float* __restrict__ invL, float* __restrict__ probs) {
  const size_t row = blockIdx.x;
  const int t = threadIdx.x;
  __shared__ float sInv;
  if (t < 64) {
    float s = (t < 8) ? Lpart[row * 8 + t] : 0.f;
    s += __shfl_xor(s, 1); s += __shfl_xor(s, 2); s += __shfl_xor(s, 4);
    if (t == 0) {
      float inv = 1.0f / s;
      sInv = inv;
      invL[row] = inv;
    }
  }
  __syncthreads();
  float inv = sInv;
  const ushort4* pv = (const ushort4*)(pb + row * 2048);
  float4* pr = (float4*)(probs + row * 2048);
  ushort4 a = pv[t * 2], b = pv[t * 2 + 1];
  float4 o0, o1;
  o0.x = bf2f(a.x) * inv; o0.y = bf2f(a.y) * inv;
  o0.z = bf2f(a.z) * inv; o0.w = bf2f(a.w) * inv;
  o1.x = bf2f(b.x) * inv; o1.y = bf2f(b.y) * inv;
  o1.z = bf2f(b.z) * inv; o1.w = bf2f(b.w) * inv;
  pr[t * 2] = o0; pr[t * 2 + 1] = o1;
}

// ---------------------------------------------------------------------------
extern "C" void kernel_launch(void* const* d_in, const int* in_sizes, int n_in,
                              void* d_out, int out_size, void* d_ws, size_t ws_size,
                              hipStream_t stream) {
  const float* x  = (const float*)d_in[0];
  const float* Wq = (const float*)d_in[1];
  const float* bq = (const float*)d_in[2];
  const float* Wk = (const float*)d_in[3];
  const float* bk = (const float*)d_in[4];
  const float* Wv = (const float*)d_in[5];
  const float* bv = (const float*)d_in[6];
  const float* Wl = (const float*)d_in[7];

  const int B = 8, S = 2048, H = 1024;
  float* out   = (float*)d_out;                     // [B,S,H]
  float* probs = (float*)d_out + (size_t)B * S * H; // [B,S,S]

  char* ws = (char*)d_ws;
  unsigned short* qkv  = (unsigned short*)(ws + 0);           // 100.7MB [16384][3072]
  unsigned short* pb   = (unsigned short*)(ws + 100663296);   // 67MB [B*S][2048] e=exp(s)
  unsigned short* xb   = (unsigned short*)(ws + 167772160);   // 33.5MB (dead after QKV GEMM)
  unsigned short* vT   = (unsigned short*)(ws + 167772160);   // 33.5MB overlays xb
  unsigned short* Wqkv = (unsigned short*)(ws + 201326592);   // 6.3MB [3072][1024]
  float* biasAll       = (float*)(ws + 207618048);            // 12KB
  float* Lpart         = (float*)(ws + 207630336);            // 512KB [16384][8]
  float* invL          = (float*)(ws + 208678912);            // 64KB [16384]

  prep_weights<<<1024, 128, 0, stream>>>(Wq, Wk, Wv, Wl, bq, bk, bv, Wqkv, biasAll);
  cast_bf16<<<16384, 256, 0, stream>>>((const float4*)x, (ushort4*)xb);

  // qkv = x @ Wqkv^T + biasAll   [16384][3072] bf16
  gemm256<0><<<dim3(12, 64, 1), 512, 0, stream>>>(xb, Wqkv, qkv, biasAll, nullptr,
      H, H, 3 * H, H, 1.f, 0, 0, 0);

  transpose_v<<<dim3(64, 32, 8), dim3(8, 32), 0, stream>>>(qkv, vT);

  // e = exp(q@k^T/32) bf16 -> pb, row-block partial sums -> Lpart
  gemm256<2><<<dim3(8, 8, 8), 512, 0, stream>>>(qkv, qkv + 1024, pb, nullptr, Lpart,
      3 * H, 3 * H, S, H, 1.0f / 32.0f, (size_t)S * 3 * H, (size_t)S * 3 * H, (size_t)S * S);

  finish_softmax<<<16384, 256, 0, stream>>>(Lpart, pb, invL, probs);

  // out = (e @ v) * invL[row]
  gemm256<3><<<dim3(4, 8, 8), 512, 0, stream>>>(pb, vT, out, invL, nullptr,
      S, S, H, S, 1.0f, (size_t)S * S, (size_t)H * S, (size_t)S * H);
}

// Round 4
// 529.897 us; speedup vs baseline: 1.0803x; 1.0215x over previous
//
#include <hip/hip_runtime.h>

typedef __attribute__((ext_vector_type(8))) short short8;
typedef __attribute__((ext_vector_type(4))) float floatx4;

__device__ __forceinline__ unsigned short f2bf(float f) {
  union { float f; unsigned int u; } x; x.f = f;
  unsigned int r = (x.u + 0x7fffu + ((x.u >> 16) & 1u)) >> 16;
  return (unsigned short)r;
}
__device__ __forceinline__ float bf2f(unsigned short u) {
  union { unsigned int u; float f; } x; x.u = ((unsigned int)u) << 16;
  return x.f;
}

__device__ __forceinline__ void gload_lds16(const void* g, void* l) {
  __builtin_amdgcn_global_load_lds((const __attribute__((address_space(1))) void*)g,
                                   (__attribute__((address_space(3))) void*)l,
                                   16, 0, 0);
}

// ---------------------------------------------------------------------------
// Prep: densify masked weights to bf16 into one [3072][1024] Wqkv buffer:
// rows 0-1023 = Wc = (Wl*mask)@(Wq*mask) (<=81 nnz/row), 1024+ = Wk*mask,
// 2048+ = Wv*mask (25 nnz). biasAll[3072] = [ (Wl*mask)@bq | bk | bv ].
// ---------------------------------------------------------------------------
__global__ __launch_bounds__(128) void prep_weights(
    const float* __restrict__ Wq, const float* __restrict__ Wk,
    const float* __restrict__ Wv, const float* __restrict__ Wl,
    const float* __restrict__ bq, const float* __restrict__ bk,
    const float* __restrict__ bv,
    unsigned short* __restrict__ Wqkv, float* __restrict__ biasAll) {
  const int i = blockIdx.x;
  const int r = i >> 5, c = i & 31;
  const int t = threadIdx.x;
  for (int p = t; p < 1024; p += 128) {
    Wqkv[i * 1024 + p] = 0;
    Wqkv[(1024 + i) * 1024 + p] = 0;
    Wqkv[(2048 + i) * 1024 + p] = 0;
  }
  __syncthreads();
  if (t < 25) {
    int dr = t / 5 - 2, dc = t % 5 - 2;
    int j = (((r + dr) & 31) << 5) | ((c + dc) & 31);
    Wqkv[(1024 + i) * 1024 + j] = f2bf(Wk[i * 1024 + j]);
    Wqkv[(2048 + i) * 1024 + j] = f2bf(Wv[i * 1024 + j]);
  }
  if (t < 81) {
    int dr = t / 9 - 4, dc = t % 9 - 4;
    int j = (((r + dr) & 31) << 5) | ((c + dc) & 31);
    float s = 0.f;
    int erlo = dr - 2 < -2 ? -2 : dr - 2, erhi = dr + 2 > 2 ? 2 : dr + 2;
    int eclo = dc - 2 < -2 ? -2 : dc - 2, echi = dc + 2 > 2 ? 2 : dc + 2;
    for (int er = erlo; er <= erhi; ++er)
      for (int ec = eclo; ec <= echi; ++ec) {
        int m = (((r + er) & 31) << 5) | ((c + ec) & 31);
        s += Wl[i * 1024 + m] * Wq[m * 1024 + j];
      }
    Wqkv[i * 1024 + j] = f2bf(s);
  }
  if (t == 96) {
    float s = 0.f;
    for (int e = 0; e < 25; ++e) {
      int dr = e / 5 - 2, dc = e % 5 - 2;
      int m = (((r + dr) & 31) << 5) | ((c + dc) & 31);
      s += Wl[i * 1024 + m] * bq[m];
    }
    biasAll[i] = s;
  }
  if (t == 97) biasAll[1024 + i] = bk[i];
  if (t == 98) biasAll[2048 + i] = bv[i];
}

// ---------------------------------------------------------------------------
__global__ __launch_bounds__(256) void cast_bf16(const float4* __restrict__ x,
                                                 ushort4* __restrict__ xb) {
  int i = blockIdx.x * 256 + threadIdx.x;
  float4 v = x[i];
  ushort4 o;
  o.x = f2bf(v.x); o.y = f2bf(v.y); o.z = f2bf(v.z); o.w = f2bf(v.w);
  xb[i] = o;
}

// ---------------------------------------------------------------------------
// 256x256-tile, BK=64, 8-wave (2Mx4N) GEMM, m201 cadence (8 phases / 2
// K-tiles, one half-tile staged per slot, counted vmcnt(4)/(6), never 0
// mid-loop), XOR swizzle (g ^ (row&7)) on stage-source and ds_read.
// NEW (r4): bijective XCD-aware block swizzle (T1/m204). Grid is launched
// 1-D flattened (bn fastest, then bm, then bz); hardware id hid round-robins
// XCDs as hid%8, so logical = (hid&7)*(nwg/8) + hid/8 gives each XCD a
// contiguous chunk of logical blocks -> blocks sharing an A-panel (12-way
// QKV / 8-way scores,PV) hit the same XCD's L2. nwg%8==0 for all launches.
// OUTMODE 0: bf16 out + fp32 bias[col]; OUTMODE 2: e=exp(acc*scale) bf16 out
// + row partials -> Lpart[row*8+bn]; OUTMODE 3: fp32 out * invL[row].
// ---------------------------------------------------------------------------
template <int OUTMODE>
__global__ __launch_bounds__(512, 2) void gemm256(
    const unsigned short* __restrict__ A, const unsigned short* __restrict__ B,
    void* __restrict__ Cv, const float* __restrict__ auxc, float* __restrict__ auxw,
    int lda, int ldb, int ldc, int K, float scale,
    size_t sA, size_t sB, size_t sC, int nx, int ny) {
  // [2 buf][A 256x64 | B 256x64] bf16 = 128 KiB
  __shared__ __align__(16) unsigned short lds[65536];
  const int t = threadIdx.x;
  const int lane = t & 63;
  const int wv = t >> 6;          // 0..7
  const int wm = wv >> 2;         // 0..1  (row half)
  const int wn = wv & 3;          // 0..3  (col quarter)
  const int l15 = lane & 15, lq = lane >> 4;

  // --- XCD-aware bijective swizzle (nwg % 8 == 0 guaranteed by launches) ---
  const int nwg = gridDim.x;
  const int hid = blockIdx.x;
  const int logical = (hid & 7) * (nwg >> 3) + (hid >> 3);
  const int bn = logical % nx;
  const int bm = (logical / nx) % ny;
  const int bz = logical / (nx * ny);

  A += sA * bz; B += sB * bz;

  const int srow = t >> 3;               // staging row within half 0..63
  const int sg = (t & 7) ^ (srow & 7);   // pre-swizzled 16B-group in source

  // Stage one half-tile (128 rows x 64 cols): 2 gload_lds x 512 thr x 16B.
#define STG_A(h, tile_) do {                                                     \
    gload_lds16(A + (size_t)(bm * 256 + (h) * 128 + srow) * lda + (tile_) * 64 + sg * 8, \
                &lds[(((tile_) & 1) << 14) + (h) * 8192 + wv * 512]);            \
    gload_lds16(A + (size_t)(bm * 256 + (h) * 128 + 64 + srow) * lda + (tile_) * 64 + sg * 8, \
                &lds[(((tile_) & 1) << 14) + (h) * 8192 + 4096 + wv * 512]);     \
  } while (0)
#define STG_B(h, tile_) do {                                                     \
    gload_lds16(B + (size_t)(bn * 256 + (h) * 128 + srow) * ldb + (tile_) * 64 + sg * 8, \
                &lds[32768 + (((tile_) & 1) << 14) + (h) * 8192 + wv * 512]);    \
    gload_lds16(B + (size_t)(bn * 256 + (h) * 128 + 64 + srow) * ldb + (tile_) * 64 + sg * 8, \
                &lds[32768 + (((tile_) & 1) << 14) + (h) * 8192 + 4096 + wv * 512]); \
  } while (0)

#define LOADA(arr, ro)                                                           \
  _Pragma("unroll") for (int i = 0; i < 4; ++i) {                                \
    int rA = wm * 128 + (ro) + i * 16 + l15;                                     \
    _Pragma("unroll") for (int ks = 0; ks < 2; ++ks)                             \
      arr[i][ks] = *(const short8*)&lds[bo_ + rA * 64 + (((ks * 4 + lq) ^ (rA & 7)) << 3)]; \
  }
#define LOADB(arr, ro)                                                           \
  _Pragma("unroll") for (int j = 0; j < 2; ++j) {                                \
    int rB = wn * 64 + (ro) + j * 16 + l15;                                      \
    _Pragma("unroll") for (int ks = 0; ks < 2; ++ks)                             \
      arr[j][ks] = *(const short8*)&lds[32768 + bo_ + rB * 64 + (((ks * 4 + lq) ^ (rB & 7)) << 3)]; \
  }
#define MFMA8(mb, nb, aa, bb)                                                    \
  _Pragma("unroll") for (int i = 0; i < 4; ++i)                                  \
    _Pragma("unroll") for (int j = 0; j < 2; ++j) {                              \
      acc[(mb) + i][(nb) + j] = __builtin_amdgcn_mfma_f32_16x16x32_bf16(         \
          aa[i][0], bb[j][0], acc[(mb) + i][(nb) + j], 0, 0, 0);                 \
      acc[(mb) + i][(nb) + j] = __builtin_amdgcn_mfma_f32_16x16x32_bf16(         \
          aa[i][1], bb[j][1], acc[(mb) + i][(nb) + j], 0, 0, 0);                 \
    }
#define FENCE asm volatile("" ::: "memory")
#define BAR __builtin_amdgcn_s_barrier()
#define SP1 __builtin_amdgcn_s_setprio(1)
#define SP0 __builtin_amdgcn_s_setprio(0)

  floatx4 acc[8][4];
#pragma unroll
  for (int i = 0; i < 8; ++i)
#pragma unroll
    for (int j = 0; j < 4; ++j) acc[i][j] = (floatx4){0.f, 0.f, 0.f, 0.f};

  const int NT = K >> 6;  // even, >= 2 (16 or 32 here)

  // Prologue: tile0 fully (8 loads) + B0,A0,B1 of tile1 (6 loads);
  // vmcnt(6) -> tile0 resident, 3 half-tiles of tile1 in flight.
  STG_A(0, 0); STG_A(1, 0); STG_B(0, 0); STG_B(1, 0);
  FENCE;
  STG_B(0, 1); STG_A(0, 1); STG_B(1, 1);
  asm volatile("s_waitcnt vmcnt(6)" ::: "memory");
  BAR;

  for (int T = 0; T < NT; T += 2) {
    short8 aF[4][2], bFa[2][2], bFb[2][2];
    // ================= tile T (buffer 0) =================
    {
      const int bo_ = 0;
      // ph1: Q(0,0)
      LOADA(aF, 0); LOADB(bFa, 0);
      STG_A(1, T + 1);
      FENCE; BAR;
      SP1; MFMA8(0, 0, aF, bFa); SP0;
      FENCE; BAR;
      // ph2: Q(0,1)
      LOADB(bFb, 32);
      FENCE; BAR;
      SP1; MFMA8(0, 2, aF, bFb); SP0;
      FENCE; BAR;
      // ph3: Q(1,1)  (reuse aF regs for upper A half)
      LOADA(aF, 64);
      if (T + 2 < NT) STG_B(0, T + 2);
      FENCE; BAR;
      SP1; MFMA8(4, 2, aF, bFb); SP0;
      FENCE; BAR;
      // ph4: Q(1,0)
      if (T + 2 < NT) STG_A(0, T + 2);
      FENCE; BAR;
      SP1; MFMA8(4, 0, aF, bFa); SP0;
      if (T + 2 < NT) { asm volatile("s_waitcnt vmcnt(4)" ::: "memory"); }
      else            { asm volatile("s_waitcnt vmcnt(0)" ::: "memory"); }
      FENCE; BAR;
    }
    // ================= tile T+1 (buffer 1) =================
    {
      const int bo_ = 1 << 14;
      // ph5: Q(0,0)
      LOADA(aF, 0); LOADB(bFa, 0);
      if (T + 2 < NT) { STG_B(1, T + 2); STG_A(1, T + 2); }
      FENCE; BAR;
      SP1; MFMA8(0, 0, aF, bFa); SP0;
      FENCE; BAR;
      // ph6: Q(0,1)
      LOADB(bFb, 32);
      FENCE; BAR;
      SP1; MFMA8(0, 2, aF, bFb); SP0;
      FENCE; BAR;
      // ph7: Q(1,1)
      LOADA(aF, 64);
      if (T + 3 < NT) STG_B(0, T + 3);
      FENCE; BAR;
      SP1; MFMA8(4, 2, aF, bFb); SP0;
      FENCE; BAR;
      // ph8: Q(1,0)
      if (T + 3 < NT) { STG_A(0, T + 3); STG_B(1, T + 3); }
      FENCE; BAR;
      SP1; MFMA8(4, 0, aF, bFa); SP0;
      if (T + 3 < NT) { asm volatile("s_waitcnt vmcnt(6)" ::: "memory"); }
      else            { asm volatile("s_waitcnt vmcnt(0)" ::: "memory"); }
      FENCE; BAR;
    }
  }
#undef STG_A
#undef STG_B
#undef LOADA
#undef LOADB
#undef MFMA8

  // acc[m][n]: row = row0 + (m>>2)*64 + (m&3)*16 + lq*4 + r2
  //            col = col0 + (n>>1)*32 + (n&1)*16 + l15
  const int row0 = bm * 256 + wm * 128;
  const int col0 = bn * 256 + wn * 64;

  if (OUTMODE == 0) {
    unsigned short* C = (unsigned short*)Cv + sC * bz;
#pragma unroll
    for (int m = 0; m < 8; ++m) {
      int rb = row0 + ((m >> 2) << 6) + ((m & 3) << 4) + (lq << 2);
#pragma unroll
      for (int n = 0; n < 4; ++n) {
        int col = col0 + ((n >> 1) << 5) + ((n & 1) << 4) + l15;
        float bb = auxc[col];
#pragma unroll
        for (int r2 = 0; r2 < 4; ++r2)
          C[(size_t)(rb + r2) * ldc + col] = f2bf(acc[m][n][r2] + bb);
      }
    }
  } else if (OUTMODE == 2) {
    unsigned short* C = (unsigned short*)Cv + sC * bz;
    float p[8][4];
#pragma unroll
    for (int m = 0; m < 8; ++m)
#pragma unroll
      for (int r2 = 0; r2 < 4; ++r2) p[m][r2] = 0.f;
#pragma unroll
    for (int m = 0; m < 8; ++m) {
      int rb = row0 + ((m >> 2) << 6) + ((m & 3) << 4) + (lq << 2);
#pragma unroll
      for (int n = 0; n < 4; ++n) {
        int col = col0 + ((n >> 1) << 5) + ((n & 1) << 4) + l15;
#pragma unroll
        for (int r2 = 0; r2 < 4; ++r2) {
          float e = __expf(acc[m][n][r2] * scale);
          C[(size_t)(rb + r2) * ldc + col] = f2bf(e);
          p[m][r2] += e;
        }
      }
    }
    // reduce over the 16 lanes (l15) sharing each row
#pragma unroll
    for (int m = 0; m < 8; ++m)
#pragma unroll
      for (int r2 = 0; r2 < 4; ++r2) {
        float v = p[m][r2];
        v += __shfl_xor(v, 1); v += __shfl_xor(v, 2);
        v += __shfl_xor(v, 4); v += __shfl_xor(v, 8);
        p[m][r2] = v;
      }
    float* sred = (float*)lds;  // [4 wn][256 rows]; all LDS traffic drained
    if (l15 == 0) {
#pragma unroll
      for (int m = 0; m < 8; ++m)
#pragma unroll
        for (int r2 = 0; r2 < 4; ++r2)
          sred[wn * 256 + wm * 128 + ((m >> 2) << 6) + ((m & 3) << 4) + (lq << 2) + r2] = p[m][r2];
    }
    __syncthreads();
    if (t < 256) {
      float L = sred[t] + sred[256 + t] + sred[512 + t] + sred[768 + t];
      auxw[((size_t)bz * 2048 + bm * 256 + t) * 8 + bn] = L;
    }
  } else {  // OUTMODE 3
    float* C = (float*)Cv + sC * bz;
#pragma unroll
    for (int m = 0; m < 8; ++m) {
      int rb = row0 + ((m >> 2) << 6) + ((m & 3) << 4) + (lq << 2);
      float il[4];
#pragma unroll
      for (int r2 = 0; r2 < 4; ++r2)
        il[r2] = auxc[(size_t)bz * 2048 + rb + r2];
#pragma unroll
      for (int n = 0; n < 4; ++n) {
        int col = col0 + ((n >> 1) << 5) + ((n & 1) << 4) + l15;
#pragma unroll
        for (int r2 = 0; r2 < 4; ++r2)
          C[(size_t)(rb + r2) * ldc + col] = acc[m][n][r2] * il[r2];
      }
    }
  }
}

// ---------------------------------------------------------------------------
// v part of qkv [16384][3072] (cols 2048+) -> vT [B][H][S] bf16.
// ushort4-vectorized both sides (8 B/lane).
// ---------------------------------------------------------------------------
__global__ __launch_bounds__(256) void transpose_v(const unsigned short* __restrict__ qkv,
                                                   unsigned short* __restrict__ vT) {
  __shared__ unsigned short tile[32][33];
  int s0 = blockIdx.x * 32, h0 = blockIdx.y * 32, b = blockIdx.z;
  int tx = threadIdx.x;  // 0..7
  int ty = threadIdx.y;  // 0..31
  ushort4 v = *(const ushort4*)&qkv[((size_t)b * 2048 + s0 + ty) * 3072 + 2048 + h0 + tx * 4];
  int c0 = tx * 4;
  tile[ty][c0 + 0] = v.x; tile[ty][c0 + 1] = v.y;
  tile[ty][c0 + 2] = v.z; tile[ty][c0 + 3] = v.w;
  __syncthreads();
  ushort4 o;
  o.x = tile[c0 + 0][ty]; o.y = tile[c0 + 1][ty];
  o.z = tile[c0 + 2][ty]; o.w = tile[c0 + 3][ty];
  *(ushort4*)&vT[((size_t)b * 1024 + h0 + ty) * 2048 + s0 + c0] = o;
}

// ---------------------------------------------------------------------------
// Finish softmax: per row, L = sum of 8 partials; invL = 1/L; write probs
// fp32 = e(bf16) * invL.  One block (256 thr) per row.
// ---------------------------------------------------------------------------
__global__ __launch_bounds__(256) void finish_softmax(
    const float* __restrict__ Lpart, const unsigned short* __restrict__ pb,
    float* __restrict__ invL, float* __restrict__ probs) {
  const size_t row = blockIdx.x;
  const int t = threadIdx.x;
  __shared__ float sInv;
  if (t < 64) {
    float s = (t < 8) ? Lpart[row * 8 + t] : 0.f;
    s += __shfl_xor(s, 1); s += __shfl_xor(s, 2); s += __shfl_xor(s, 4);
    if (t == 0) {
      float inv = 1.0f / s;
      sInv = inv;
      invL[row] = inv;
    }
  }
  __syncthreads();
  float inv = sInv;
  const ushort4* pv = (const ushort4*)(pb + row * 2048);
  float4* pr = (float4*)(probs + row * 2048);
  ushort4 a = pv[t * 2], b = pv[t * 2 + 1];
  float4 o0, o1;
  o0.x = bf2f(a.x) * inv; o0.y = bf2f(a.y) * inv;
  o0.z = bf2f(a.z) * inv; o0.w = bf2f(a.w) * inv;
  o1.x = bf2f(b.x) * inv; o1.y = bf2f(b.y) * inv;
  o1.z = bf2f(b.z) * inv; o1.w = bf2f(b.w) * inv;
  pr[t * 2] = o0; pr[t * 2 + 1] = o1;
}

// ---------------------------------------------------------------------------
extern "C" void kernel_launch(void* const* d_in, const int* in_sizes, int n_in,
                              void* d_out, int out_size, void* d_ws, size_t ws_size,
                              hipStream_t stream) {
  const float* x  = (const float*)d_in[0];
  const float* Wq = (const float*)d_in[1];
  const float* bq = (const float*)d_in[2];
  const float* Wk = (const float*)d_in[3];
  const float* bk = (const float*)d_in[4];
  const float* Wv = (const float*)d_in[5];
  const float* bv = (const float*)d_in[6];
  const float* Wl = (const float*)d_in[7];

  const int B = 8, S = 2048, H = 1024;
  float* out   = (float*)d_out;                     // [B,S,H]
  float* probs = (float*)d_out + (size_t)B * S * H; // [B,S,S]

  char* ws = (char*)d_ws;
  unsigned short* qkv  = (unsigned short*)(ws + 0);           // 100.7MB [16384][3072]
  unsigned short* pb   = (unsigned short*)(ws + 100663296);   // 67MB [B*S][2048] e=exp(s)
  unsigned short* xb   = (unsigned short*)(ws + 167772160);   // 33.5MB (dead after QKV GEMM)
  unsigned short* vT   = (unsigned short*)(ws + 167772160);   // 33.5MB overlays xb
  unsigned short* Wqkv = (unsigned short*)(ws + 201326592);   // 6.3MB [3072][1024]
  float* biasAll       = (float*)(ws + 207618048);            // 12KB
  float* Lpart         = (float*)(ws + 207630336);            // 512KB [16384][8]
  float* invL          = (float*)(ws + 208678912);            // 64KB [16384]

  prep_weights<<<1024, 128, 0, stream>>>(Wq, Wk, Wv, Wl, bq, bk, bv, Wqkv, biasAll);
  cast_bf16<<<16384, 256, 0, stream>>>((const float4*)x, (ushort4*)xb);

  // qkv = x @ Wqkv^T + biasAll   [16384][3072] bf16   (flat grid 12*64)
  gemm256<0><<<768, 512, 0, stream>>>(xb, Wqkv, qkv, biasAll, nullptr,
      H, H, 3 * H, H, 1.f, 0, 0, 0, 12, 64);

  transpose_v<<<dim3(64, 32, 8), dim3(8, 32), 0, stream>>>(qkv, vT);

  // e = exp(q@k^T/32) bf16 -> pb, row-block partial sums -> Lpart (8*8*8)
  gemm256<2><<<512, 512, 0, stream>>>(qkv, qkv + 1024, pb, nullptr, Lpart,
      3 * H, 3 * H, S, H, 1.0f / 32.0f, (size_t)S * 3 * H, (size_t)S * 3 * H, (size_t)S * S, 8, 8);

  finish_softmax<<<16384, 256, 0, stream>>>(Lpart, pb, invL, probs);

  // out = (e @ v) * invL[row]   (4*8*8)
  gemm256<3><<<256, 512, 0, stream>>>(pb, vT, out, invL, nullptr,
      S, S, H, S, 1.0f, (size_t)S * S, (size_t)H * S, (size_t)S * H, 4, 8);
}

// Round 5
// 526.249 us; speedup vs baseline: 1.0878x; 1.0069x over previous
//
#include <hip/hip_runtime.h>

typedef __attribute__((ext_vector_type(8))) short short8;
typedef __attribute__((ext_vector_type(4))) float floatx4;

__device__ __forceinline__ unsigned short f2bf(float f) {
  union { float f; unsigned int u; } x; x.f = f;
  unsigned int r = (x.u + 0x7fffu + ((x.u >> 16) & 1u)) >> 16;
  return (unsigned short)r;
}
__device__ __forceinline__ float bf2f(unsigned short u) {
  union { unsigned int u; float f; } x; x.u = ((unsigned int)u) << 16;
  return x.f;
}

__device__ __forceinline__ void gload_lds16(const void* g, void* l) {
  __builtin_amdgcn_global_load_lds((const __attribute__((address_space(1))) void*)g,
                                   (__attribute__((address_space(3))) void*)l,
                                   16, 0, 0);
}

// ---------------------------------------------------------------------------
// Prep: densify masked weights to bf16 into one [3072][1024] Wqkv buffer:
// rows 0-1023 = Wc = (Wl*mask)@(Wq*mask) (<=81 nnz/row), 1024+ = Wk*mask,
// 2048+ = Wv*mask (25 nnz). biasAll[3072] = [ (Wl*mask)@bq | bk | bv ].
// ---------------------------------------------------------------------------
__global__ __launch_bounds__(128) void prep_weights(
    const float* __restrict__ Wq, const float* __restrict__ Wk,
    const float* __restrict__ Wv, const float* __restrict__ Wl,
    const float* __restrict__ bq, const float* __restrict__ bk,
    const float* __restrict__ bv,
    unsigned short* __restrict__ Wqkv, float* __restrict__ biasAll) {
  const int i = blockIdx.x;
  const int r = i >> 5, c = i & 31;
  const int t = threadIdx.x;
  // vectorized zero-fill: 1024 elems = 128 x short8 per row, 128 threads
  {
    short8 z = (short8){0, 0, 0, 0, 0, 0, 0, 0};
    ((short8*)Wqkv)[i * 128 + t] = z;
    ((short8*)Wqkv)[(1024 + i) * 128 + t] = z;
    ((short8*)Wqkv)[(2048 + i) * 128 + t] = z;
  }
  __syncthreads();
  if (t < 25) {
    int dr = t / 5 - 2, dc = t % 5 - 2;
    int j = (((r + dr) & 31) << 5) | ((c + dc) & 31);
    Wqkv[(1024 + i) * 1024 + j] = f2bf(Wk[i * 1024 + j]);
    Wqkv[(2048 + i) * 1024 + j] = f2bf(Wv[i * 1024 + j]);
  }
  if (t < 81) {
    int dr = t / 9 - 4, dc = t % 9 - 4;
    int j = (((r + dr) & 31) << 5) | ((c + dc) & 31);
    float s = 0.f;
    int erlo = dr - 2 < -2 ? -2 : dr - 2, erhi = dr + 2 > 2 ? 2 : dr + 2;
    int eclo = dc - 2 < -2 ? -2 : dc - 2, echi = dc + 2 > 2 ? 2 : dc + 2;
    for (int er = erlo; er <= erhi; ++er)
      for (int ec = eclo; ec <= echi; ++ec) {
        int m = (((r + er) & 31) << 5) | ((c + ec) & 31);
        s += Wl[i * 1024 + m] * Wq[m * 1024 + j];
      }
    Wqkv[i * 1024 + j] = f2bf(s);
  }
  if (t == 96) {
    float s = 0.f;
    for (int e = 0; e < 25; ++e) {
      int dr = e / 5 - 2, dc = e % 5 - 2;
      int m = (((r + dr) & 31) << 5) | ((c + dc) & 31);
      s += Wl[i * 1024 + m] * bq[m];
    }
    biasAll[i] = s;
  }
  if (t == 97) biasAll[1024 + i] = bk[i];
  if (t == 98) biasAll[2048 + i] = bv[i];
}

// ---------------------------------------------------------------------------
__global__ __launch_bounds__(256) void cast_bf16(const float4* __restrict__ x,
                                                 ushort4* __restrict__ xb) {
  int i = blockIdx.x * 256 + threadIdx.x;
  float4 v = x[i];
  ushort4 o;
  o.x = f2bf(v.x); o.y = f2bf(v.y); o.z = f2bf(v.z); o.w = f2bf(v.w);
  xb[i] = o;
}

// ---------------------------------------------------------------------------
// 256x256-tile, BK=64, 8-wave (2Mx4N) GEMM, m201 cadence (8 phases / 2
// K-tiles, one half-tile staged per slot, counted vmcnt(4)/(6), never 0
// mid-loop), XOR swizzle (g ^ (row&7)) on stage-source and ds_read,
// bijective XCD-aware block swizzle (flat grid, bn fastest).
// OUTMODE 0: bf16 out + fp32 bias[col] (QKV). Blocks with bn<8 write q/k to
//   qkv; blocks with bn>=8 hold the V tile -> write bias-added V DIRECTLY
//   TRANSPOSED to vT[b][h][s] via an LDS [256][264] tile (fused transpose_v).
// OUTMODE 2: e=exp(acc*scale) bf16 out + row partials -> Lpart[row*8+bn]
// OUTMODE 3: fp32 out * invL[row] (PV with deferred softmax normalization)
// ---------------------------------------------------------------------------
template <int OUTMODE>
__global__ __launch_bounds__(512, 2) void gemm256(
    const unsigned short* __restrict__ A, const unsigned short* __restrict__ B,
    void* __restrict__ Cv, const float* __restrict__ auxc, float* __restrict__ auxw,
    int lda, int ldb, int ldc, int K, float scale,
    size_t sA, size_t sB, size_t sC, int nx, int ny) {
  // K-loop: [2 buf][A 256x64 | B 256x64] bf16 = 128 KiB.
  // OUTMODE 0 epilogue reuses it as [256][264] ushort transpose tile (132 KiB).
  __shared__ __align__(16) unsigned short lds[67584];
  const int t = threadIdx.x;
  const int lane = t & 63;
  const int wv = t >> 6;          // 0..7
  const int wm = wv >> 2;         // 0..1  (row half)
  const int wn = wv & 3;          // 0..3  (col quarter)
  const int l15 = lane & 15, lq = lane >> 4;

  // --- XCD-aware bijective swizzle (nwg % 8 == 0 guaranteed by launches) ---
  const int nwg = gridDim.x;
  const int hid = blockIdx.x;
  const int logical = (hid & 7) * (nwg >> 3) + (hid >> 3);
  const int bn = logical % nx;
  const int bm = (logical / nx) % ny;
  const int bz = logical / (nx * ny);

  A += sA * bz; B += sB * bz;

  const int srow = t >> 3;               // staging row within half 0..63
  const int sg = (t & 7) ^ (srow & 7);   // pre-swizzled 16B-group in source

  // Stage one half-tile (128 rows x 64 cols): 2 gload_lds x 512 thr x 16B.
#define STG_A(h, tile_) do {                                                     \
    gload_lds16(A + (size_t)(bm * 256 + (h) * 128 + srow) * lda + (tile_) * 64 + sg * 8, \
                &lds[(((tile_) & 1) << 14) + (h) * 8192 + wv * 512]);            \
    gload_lds16(A + (size_t)(bm * 256 + (h) * 128 + 64 + srow) * lda + (tile_) * 64 + sg * 8, \
                &lds[(((tile_) & 1) << 14) + (h) * 8192 + 4096 + wv * 512]);     \
  } while (0)
#define STG_B(h, tile_) do {                                                     \
    gload_lds16(B + (size_t)(bn * 256 + (h) * 128 + srow) * ldb + (tile_) * 64 + sg * 8, \
                &lds[32768 + (((tile_) & 1) << 14) + (h) * 8192 + wv * 512]);    \
    gload_lds16(B + (size_t)(bn * 256 + (h) * 128 + 64 + srow) * ldb + (tile_) * 64 + sg * 8, \
                &lds[32768 + (((tile_) & 1) << 14) + (h) * 8192 + 4096 + wv * 512]); \
  } while (0)

#define LOADA(arr, ro)                                                           \
  _Pragma("unroll") for (int i = 0; i < 4; ++i) {                                \
    int rA = wm * 128 + (ro) + i * 16 + l15;                                     \
    _Pragma("unroll") for (int ks = 0; ks < 2; ++ks)                             \
      arr[i][ks] = *(const short8*)&lds[bo_ + rA * 64 + (((ks * 4 + lq) ^ (rA & 7)) << 3)]; \
  }
#define LOADB(arr, ro)                                                           \
  _Pragma("unroll") for (int j = 0; j < 2; ++j) {                                \
    int rB = wn * 64 + (ro) + j * 16 + l15;                                      \
    _Pragma("unroll") for (int ks = 0; ks < 2; ++ks)                             \
      arr[j][ks] = *(const short8*)&lds[32768 + bo_ + rB * 64 + (((ks * 4 + lq) ^ (rB & 7)) << 3)]; \
  }
#define MFMA8(mb, nb, aa, bb)                                                    \
  _Pragma("unroll") for (int i = 0; i < 4; ++i)                                  \
    _Pragma("unroll") for (int j = 0; j < 2; ++j) {                              \
      acc[(mb) + i][(nb) + j] = __builtin_amdgcn_mfma_f32_16x16x32_bf16(         \
          aa[i][0], bb[j][0], acc[(mb) + i][(nb) + j], 0, 0, 0);                 \
      acc[(mb) + i][(nb) + j] = __builtin_amdgcn_mfma_f32_16x16x32_bf16(         \
          aa[i][1], bb[j][1], acc[(mb) + i][(nb) + j], 0, 0, 0);                 \
    }
#define FENCE asm volatile("" ::: "memory")
#define BAR __builtin_amdgcn_s_barrier()
#define SP1 __builtin_amdgcn_s_setprio(1)
#define SP0 __builtin_amdgcn_s_setprio(0)

  floatx4 acc[8][4];
#pragma unroll
  for (int i = 0; i < 8; ++i)
#pragma unroll
    for (int j = 0; j < 4; ++j) acc[i][j] = (floatx4){0.f, 0.f, 0.f, 0.f};

  const int NT = K >> 6;  // even, >= 2 (16 or 32 here)

  // Prologue: tile0 fully (8 loads) + B0,A0,B1 of tile1 (6 loads);
  // vmcnt(6) -> tile0 resident, 3 half-tiles of tile1 in flight.
  STG_A(0, 0); STG_A(1, 0); STG_B(0, 0); STG_B(1, 0);
  FENCE;
  STG_B(0, 1); STG_A(0, 1); STG_B(1, 1);
  asm volatile("s_waitcnt vmcnt(6)" ::: "memory");
  BAR;

  for (int T = 0; T < NT; T += 2) {
    short8 aF[4][2], bFa[2][2], bFb[2][2];
    // ================= tile T (buffer 0) =================
    {
      const int bo_ = 0;
      // ph1: Q(0,0)
      LOADA(aF, 0); LOADB(bFa, 0);
      STG_A(1, T + 1);
      FENCE; BAR;
      SP1; MFMA8(0, 0, aF, bFa); SP0;
      FENCE; BAR;
      // ph2: Q(0,1)
      LOADB(bFb, 32);
      FENCE; BAR;
      SP1; MFMA8(0, 2, aF, bFb); SP0;
      FENCE; BAR;
      // ph3: Q(1,1)  (reuse aF regs for upper A half)
      LOADA(aF, 64);
      if (T + 2 < NT) STG_B(0, T + 2);
      FENCE; BAR;
      SP1; MFMA8(4, 2, aF, bFb); SP0;
      FENCE; BAR;
      // ph4: Q(1,0)
      if (T + 2 < NT) STG_A(0, T + 2);
      FENCE; BAR;
      SP1; MFMA8(4, 0, aF, bFa); SP0;
      if (T + 2 < NT) { asm volatile("s_waitcnt vmcnt(4)" ::: "memory"); }
      else            { asm volatile("s_waitcnt vmcnt(0)" ::: "memory"); }
      FENCE; BAR;
    }
    // ================= tile T+1 (buffer 1) =================
    {
      const int bo_ = 1 << 14;
      // ph5: Q(0,0)
      LOADA(aF, 0); LOADB(bFa, 0);
      if (T + 2 < NT) { STG_B(1, T + 2); STG_A(1, T + 2); }
      FENCE; BAR;
      SP1; MFMA8(0, 0, aF, bFa); SP0;
      FENCE; BAR;
      // ph6: Q(0,1)
      LOADB(bFb, 32);
      FENCE; BAR;
      SP1; MFMA8(0, 2, aF, bFb); SP0;
      FENCE; BAR;
      // ph7: Q(1,1)
      LOADA(aF, 64);
      if (T + 3 < NT) STG_B(0, T + 3);
      FENCE; BAR;
      SP1; MFMA8(4, 2, aF, bFb); SP0;
      FENCE; BAR;
      // ph8: Q(1,0)
      if (T + 3 < NT) { STG_A(0, T + 3); STG_B(1, T + 3); }
      FENCE; BAR;
      SP1; MFMA8(4, 0, aF, bFa); SP0;
      if (T + 3 < NT) { asm volatile("s_waitcnt vmcnt(6)" ::: "memory"); }
      else            { asm volatile("s_waitcnt vmcnt(0)" ::: "memory"); }
      FENCE; BAR;
    }
  }
#undef STG_A
#undef STG_B
#undef LOADA
#undef LOADB
#undef MFMA8

  // acc[m][n]: row = row0 + (m>>2)*64 + (m&3)*16 + lq*4 + r2
  //            col = col0 + (n>>1)*32 + (n&1)*16 + l15
  const int row0 = bm * 256 + wm * 128;
  const int col0 = bn * 256 + wn * 64;

  if (OUTMODE == 0) {
    if (bn < 8) {
      // q/k blocks: normal bf16 write + bias
      unsigned short* C = (unsigned short*)Cv;
#pragma unroll
      for (int m = 0; m < 8; ++m) {
        int rb = row0 + ((m >> 2) << 6) + ((m & 3) << 4) + (lq << 2);
#pragma unroll
        for (int n = 0; n < 4; ++n) {
          int col = col0 + ((n >> 1) << 5) + ((n & 1) << 4) + l15;
          float bb = auxc[col];
#pragma unroll
          for (int r2 = 0; r2 < 4; ++r2)
            C[(size_t)(rb + r2) * ldc + col] = f2bf(acc[m][n][r2] + bb);
        }
      }
    } else {
      // v blocks: bias + transpose via LDS -> vT[b][h][s] (fused transpose_v)
      unsigned short (*lds2)[264] = (unsigned short (*)[264])lds;
      // K-loop fully drained (final vmcnt(0) + barrier; all ds_reads consumed
      // pre-barrier) -> LDS reusable without an extra barrier.
#pragma unroll
      for (int m = 0; m < 8; ++m) {
        int sr = wm * 128 + ((m >> 2) << 6) + ((m & 3) << 4) + (lq << 2);
#pragma unroll
        for (int n = 0; n < 4; ++n) {
          int colg = col0 + ((n >> 1) << 5) + ((n & 1) << 4) + l15;  // 2048..3071
          int h = (colg - 2048) & 255;  // local h within this block's 256 cols
          float bb = auxc[colg];
          ushort4 pk;
          pk.x = f2bf(acc[m][n][0] + bb);
          pk.y = f2bf(acc[m][n][1] + bb);
          pk.z = f2bf(acc[m][n][2] + bb);
          pk.w = f2bf(acc[m][n][3] + bb);
          *(ushort4*)&lds2[h][sr] = pk;  // 8B write, s-contiguous
        }
      }
      __syncthreads();
      unsigned short* vTp = (unsigned short*)auxw;
      const int b = bm >> 3;
      const int s0 = (bm & 7) * 256;
      const int h0 = (bn - 8) * 256;
      const int hh = t >> 1, sh = (t & 1) * 128;
      unsigned short* dst = vTp + ((size_t)b * 1024 + h0 + hh) * 2048 + s0 + sh;
      const unsigned short* src = &lds2[hh][sh];
#pragma unroll
      for (int k2 = 0; k2 < 16; ++k2)
        *(short8*)&dst[k2 * 8] = *(const short8*)&src[k2 * 8];
    }
  } else if (OUTMODE == 2) {
    unsigned short* C = (unsigned short*)Cv + sC * bz;
    float p[8][4];
#pragma unroll
    for (int m = 0; m < 8; ++m)
#pragma unroll
      for (int r2 = 0; r2 < 4; ++r2) p[m][r2] = 0.f;
#pragma unroll
    for (int m = 0; m < 8; ++m) {
      int rb = row0 + ((m >> 2) << 6) + ((m & 3) << 4) + (lq << 2);
#pragma unroll
      for (int n = 0; n < 4; ++n) {
        int col = col0 + ((n >> 1) << 5) + ((n & 1) << 4) + l15;
#pragma unroll
        for (int r2 = 0; r2 < 4; ++r2) {
          float e = __expf(acc[m][n][r2] * scale);
          C[(size_t)(rb + r2) * ldc + col] = f2bf(e);
          p[m][r2] += e;
        }
      }
    }
    // reduce over the 16 lanes (l15) sharing each row
#pragma unroll
    for (int m = 0; m < 8; ++m)
#pragma unroll
      for (int r2 = 0; r2 < 4; ++r2) {
        float v = p[m][r2];
        v += __shfl_xor(v, 1); v += __shfl_xor(v, 2);
        v += __shfl_xor(v, 4); v += __shfl_xor(v, 8);
        p[m][r2] = v;
      }
    float* sred = (float*)lds;  // [4 wn][256 rows]; all LDS traffic drained
    if (l15 == 0) {
#pragma unroll
      for (int m = 0; m < 8; ++m)
#pragma unroll
        for (int r2 = 0; r2 < 4; ++r2)
          sred[wn * 256 + wm * 128 + ((m >> 2) << 6) + ((m & 3) << 4) + (lq << 2) + r2] = p[m][r2];
    }
    __syncthreads();
    if (t < 256) {
      float L = sred[t] + sred[256 + t] + sred[512 + t] + sred[768 + t];
      auxw[((size_t)bz * 2048 + bm * 256 + t) * 8 + bn] = L;
    }
  } else {  // OUTMODE 3
    float* C = (float*)Cv + sC * bz;
#pragma unroll
    for (int m = 0; m < 8; ++m) {
      int rb = row0 + ((m >> 2) << 6) + ((m & 3) << 4) + (lq << 2);
      float il[4];
#pragma unroll
      for (int r2 = 0; r2 < 4; ++r2)
        il[r2] = auxc[(size_t)bz * 2048 + rb + r2];
#pragma unroll
      for (int n = 0; n < 4; ++n) {
        int col = col0 + ((n >> 1) << 5) + ((n & 1) << 4) + l15;
#pragma unroll
        for (int r2 = 0; r2 < 4; ++r2)
          C[(size_t)(rb + r2) * ldc + col] = acc[m][n][r2] * il[r2];
      }
    }
  }
}

// ---------------------------------------------------------------------------
// Finish softmax: per row, L = sum of 8 partials; invL = 1/L; write probs
// fp32 = e(bf16) * invL.  One block (256 thr) per row.
// ---------------------------------------------------------------------------
__global__ __launch_bounds__(256) void finish_softmax(
    const float* __restrict__ Lpart, const unsigned short* __restrict__ pb,
    float* __restrict__ invL, float* __restrict__ probs) {
  const size_t row = blockIdx.x;
  const int t = threadIdx.x;
  __shared__ float sInv;
  if (t < 64) {
    float s = (t < 8) ? Lpart[row * 8 + t] : 0.f;
    s += __shfl_xor(s, 1); s += __shfl_xor(s, 2); s += __shfl_xor(s, 4);
    if (t == 0) {
      float inv = 1.0f / s;
      sInv = inv;
      invL[row] = inv;
    }
  }
  __syncthreads();
  float inv = sInv;
  const ushort4* pv = (const ushort4*)(pb + row * 2048);
  float4* pr = (float4*)(probs + row * 2048);
  ushort4 a = pv[t * 2], b = pv[t * 2 + 1];
  float4 o0, o1;
  o0.x = bf2f(a.x) * inv; o0.y = bf2f(a.y) * inv;
  o0.z = bf2f(a.z) * inv; o0.w = bf2f(a.w) * inv;
  o1.x = bf2f(b.x) * inv; o1.y = bf2f(b.y) * inv;
  o1.z = bf2f(b.z) * inv; o1.w = bf2f(b.w) * inv;
  pr[t * 2] = o0; pr[t * 2 + 1] = o1;
}

// ---------------------------------------------------------------------------
extern "C" void kernel_launch(void* const* d_in, const int* in_sizes, int n_in,
                              void* d_out, int out_size, void* d_ws, size_t ws_size,
                              hipStream_t stream) {
  const float* x  = (const float*)d_in[0];
  const float* Wq = (const float*)d_in[1];
  const float* bq = (const float*)d_in[2];
  const float* Wk = (const float*)d_in[3];
  const float* bk = (const float*)d_in[4];
  const float* Wv = (const float*)d_in[5];
  const float* bv = (const float*)d_in[6];
  const float* Wl = (const float*)d_in[7];

  const int B = 8, S = 2048, H = 1024;
  float* out   = (float*)d_out;                     // [B,S,H]
  float* probs = (float*)d_out + (size_t)B * S * H; // [B,S,S]

  char* ws = (char*)d_ws;
  unsigned short* qkv  = (unsigned short*)(ws + 0);           // 100.7MB [16384][3072] (v third unused)
  unsigned short* pb   = (unsigned short*)(ws + 100663296);   // 67MB [B*S][2048] e=exp(s)
  unsigned short* xb   = (unsigned short*)(ws + 167772160);   // 33.5MB (dead after QKV GEMM)
  unsigned short* vT   = (unsigned short*)(ws + 167772160);   // 33.5MB overlays xb... NO: vT now written
                                                              // during QKV while xb is still live ->
                                                              // separate region below.
  unsigned short* Wqkv = (unsigned short*)(ws + 201326592);   // 6.3MB [3072][1024]
  float* biasAll       = (float*)(ws + 207618048);            // 12KB
  float* Lpart         = (float*)(ws + 207630336);            // 512KB [16384][8]
  float* invL          = (float*)(ws + 208678912);            // 64KB [16384]
  vT = (unsigned short*)(ws + 209715200);                     // 33.5MB [B][H][S] (own region)

  prep_weights<<<1024, 128, 0, stream>>>(Wq, Wk, Wv, Wl, bq, bk, bv, Wqkv, biasAll);
  cast_bf16<<<16384, 256, 0, stream>>>((const float4*)x, (ushort4*)xb);

  // qkv(q,k) = x @ Wqkv^T + biasAll; v written transposed to vT (fused)
  gemm256<0><<<768, 512, 0, stream>>>(xb, Wqkv, qkv, biasAll, (float*)vT,
      H, H, 3 * H, H, 1.f, 0, 0, 0, 12, 64);

  // e = exp(q@k^T/32) bf16 -> pb, row-block partial sums -> Lpart (8*8*8)
  gemm256<2><<<512, 512, 0, stream>>>(qkv, qkv + 1024, pb, nullptr, Lpart,
      3 * H, 3 * H, S, H, 1.0f / 32.0f, (size_t)S * 3 * H, (size_t)S * 3 * H, (size_t)S * S, 8, 8);

  finish_softmax<<<16384, 256, 0, stream>>>(Lpart, pb, invL, probs);

  // out = (e @ v) * invL[row]   (4*8*8)
  gemm256<3><<<256, 512, 0, stream>>>(pb, vT, out, invL, nullptr,
      S, S, H, S, 1.0f, (size_t)S * S, (size_t)H * S, (size_t)S * H, 4, 8);
}